// Round 8
// baseline (514.079 us; speedup 1.0000x reference)
//
#include <hip/hip_runtime.h>

// Problem constants (match reference)
#define OUT_F 4096   // M
#define IN_F  4096   // K
#define NCOLS 8192   // N

#define GM OUT_F
#define GK IN_F
#define GN NCOLS

typedef __attribute__((ext_vector_type(8))) short short8;
typedef __attribute__((ext_vector_type(4))) float f32x4;
typedef __attribute__((ext_vector_type(16))) float f32x16;

// ---------------------------------------------------------------------------
// helpers
// ---------------------------------------------------------------------------
__device__ inline unsigned short f2bf(float f) {
    union { float f; unsigned u; } c; c.f = f;
    unsigned u = c.u;
    u += 0x7fffu + ((u >> 16) & 1u);   // round-to-nearest-even
    return (unsigned short)(u >> 16);
}

__device__ inline void gll16(const void* g, void* l) {
    __builtin_amdgcn_global_load_lds(
        (const __attribute__((address_space(1))) unsigned int*)g,
        (__attribute__((address_space(3))) unsigned int*)l, 16, 0, 0);
}

// ---------------------------------------------------------------------------
// Densify path
// ---------------------------------------------------------------------------
__global__ void scatter_dense(const int* __restrict__ rows, const int* __restrict__ cols,
                              const float* __restrict__ vals, float* __restrict__ W, int nnz) {
    int i = blockIdx.x * blockDim.x + threadIdx.x;
    if (i < nnz) atomicAdd(&W[(size_t)rows[i] * IN_F + cols[i]], vals[i]);
}

__global__ void convert_w(const float* __restrict__ Wf, unsigned short* __restrict__ Wb) {
    int i = blockIdx.x * blockDim.x + threadIdx.x;  // over elems/4
    float4 v = ((const float4*)Wf)[i];
    ushort4 o;
    o.x = f2bf(v.x); o.y = f2bf(v.y); o.z = f2bf(v.z); o.w = f2bf(v.w);
    ((ushort4*)Wb)[i] = o;
}

// x [IN_F][NCOLS] f32 -> xT [NCOLS][IN_F] bf16, 64x64 tiles via LDS
__global__ __launch_bounds__(256) void transpose_x(const float* __restrict__ x,
                                                   unsigned short* __restrict__ xT) {
    __shared__ float tile[64][65];
    const int k0 = blockIdx.x * 64;   // x row block (K dim)
    const int n0 = blockIdx.y * 64;   // x col block (N dim)
    const int t = threadIdx.x;
    const int c4 = (t & 15) * 4;
    const int r0 = t >> 4;            // 0..15
    for (int p = 0; p < 4; ++p) {
        int r = r0 + p * 16;
        float4 v = *(const float4*)&x[(size_t)(k0 + r) * NCOLS + n0 + c4];
        tile[r][c4 + 0] = v.x; tile[r][c4 + 1] = v.y;
        tile[r][c4 + 2] = v.z; tile[r][c4 + 3] = v.w;
    }
    __syncthreads();
    const int n  = t >> 2;            // 0..63
    const int ks = (t & 3) * 16;      // 0,16,32,48
    unsigned w[8];
    for (int m = 0; m < 8; ++m) {
        unsigned short lo = f2bf(tile[ks + 2 * m + 0][n]);
        unsigned short hi = f2bf(tile[ks + 2 * m + 1][n]);
        w[m] = (unsigned)lo | ((unsigned)hi << 16);
    }
    uint4* dst = (uint4*)&xT[(size_t)(n0 + n) * GK + k0 + ks];
    dst[0] = make_uint4(w[0], w[1], w[2], w[3]);
    dst[1] = make_uint4(w[4], w[5], w[6], w[7]);
}

// ---------------------------------------------------------------------------
// GEMM: C[GM][GN] f32 = A(bf16 [GM][GK]) * B, with B given as BT bf16 [GN][GK].
// R8: R7 schedule unchanged; MFMA shape 16x16x32 -> 32x32x16 (m119: 2495 vs
//   ~2176 TF pipe ceiling, floor 1242 -> 1033 cyc/phase; half the MFMA insts).
//   256x256 tile, 512 thr = 8 waves (2M x 4N), per-wave out 128x64.
//   LDS = 4 rotating slots of 32 KB (slot = A 256x32k | B 256x32k), BK=32/phase.
//   Phase p (slot e = p&3):
//     s_waitcnt vmcnt(4)      // retires stage@p-2 (tile p+1) -- counted, never 0
//     s_barrier               // seals slot (p+1)&3 cross-wave
//     sched_barrier(0)        // reads may not hoist above the seal
//     ds_read af2 (slot e, A row-blocks 2,3)                   4x b128
//     ds_read bfN, afN (slot (e+1)&3, row-blocks 0,1)          8x b128
//     STAGE tile p+3 -> slot (p+3)&3                           4x gll16
//     sched_barrier(0)        // reads/stage may not sink below
//     setprio(1)
//     8 MFMA 32x32x16: acc[0,1][*] += afC x bfC  (regs read @p-1)
//     8 MFMA 32x32x16: acc[2,3][*] += af2 x bfC  (af2 read @p)
//     setprio(0)
//   Fragment maps (32x32x16): A/B lane l holds row/col (l&31), 8 contiguous k
//   at k-block (l>>5); C/D col=lane&31, row=(reg&3)+8*(reg>>2)+4*(lane>>5).
//   Swizzle (R2-verified): 64B row = 4x16B slots; logical k-block j of row r at
//   slot j^((r>>1)&3); pre-swizzled global source, same involution on reads.
//   Read bank check: 64 lanes spread 8 per 16B bank-group over all 8 groups.
//   wg swizzle: XCD-aware + N-banded (R5-verified: FETCH 625->199 MB).
// ---------------------------------------------------------------------------
__global__ __launch_bounds__(512, 2) void gemm256(const unsigned short* __restrict__ A,
                                                  const unsigned short* __restrict__ BT,
                                                  float* __restrict__ C) {
    __shared__ unsigned short lds[65536];   // 128 KiB = 4 slots x 16384 elems

    const int tid  = threadIdx.x;
    const int wave = tid >> 6;
    const int lane = tid & 63;

    // XCD-aware, N-banded bijective swizzle (nwg = 512)
    const int wg   = blockIdx.y * 32 + blockIdx.x;
    const int xcd  = wg & 7;
    const int ii   = wg >> 3;                       // 0..63
    const int m0   = ((((ii & 7) << 1) | (xcd & 1))) << 8;         // 16 M-tiles
    const int n0   = ((((ii >> 3) << 2) | ((xcd >> 1) & 3))) << 8; // 32 N-tiles, banded by 4
    const int wm = wave >> 2;          // 0..1  (M half of tile)
    const int wn = wave & 3;           // 0..3  (N quarter of tile)

    // ---- staging: chunk c = q*512 + tid; row = c>>2 (0..127 q=0, +128 q=1), slot = c&3.
    // fetch global k-block (c&3)^((row>>1)&3) so linear LDS slot holds swizzled data.
    const int r0s  = tid >> 2;                              // 0..127
    const int swz0 = ((tid & 3) ^ ((r0s >> 1) & 3)) << 3;   // elems
    const unsigned short* pA0 = A  + (size_t)(m0 + r0s) * GK + swz0;
    const unsigned short* pA1 = pA0 + (size_t)128 * GK;
    const unsigned short* pB0 = BT + (size_t)(n0 + r0s) * GK + swz0;
    const unsigned short* pB1 = pB0 + (size_t)128 * GK;

    // ---- fragment mapping (32x32x16): frow32 = lane&31, k-block jsel = lane>>5
    // A row r = wm*128 + mb*32 + frow32; B row r = wn*64 + nb*32 + frow32.
    // All non-frow32 terms == 0 mod 8 -> (r>>1)&3 == (frow32>>1)&3.
    const int frow32 = lane & 31;
    const int jsel   = lane >> 5;                 // 0..1
    const int q32    = (frow32 >> 1) & 3;
    const int sw0    = ((jsel ^ q32) << 3);       // kk=0: logical block jsel
    const int sw1    = (((2 | jsel) ^ q32) << 3); // kk=1: logical block 2+jsel
    const int abase32 = ((wm << 7) + frow32) << 5;          // A elem offset in slot
    const int bbase32 = 8192 + (((wn << 6) + frow32) << 5); // B elem offset in slot

    f32x16 acc[4][2] = {};   // [mb][nb], 32x32 each

    // stage K-tile T_ into slot s_ (4 gll16/thread; dest wave-uniform + lane*16)
#define STAGE(T_, s_) do {                                              \
        const int ko_ = ((T_) & 127) << 5;                              \
        gll16(pA0 + ko_, &lds[(s_) * 16384 + (wave << 9)]);             \
        gll16(pA1 + ko_, &lds[(s_) * 16384 + 4096 + (wave << 9)]);      \
        gll16(pB0 + ko_, &lds[(s_) * 16384 + 8192 + (wave << 9)]);      \
        gll16(pB1 + ko_, &lds[(s_) * 16384 + 12288 + (wave << 9)]);     \
    } while (0)

    // prologue: tiles 0,1,2 -> slots 0,1,2; tile 0 resident; phase-0 frags read
    STAGE(0, 0); STAGE(1, 1); STAGE(2, 2);
    asm volatile("s_waitcnt vmcnt(8)");
    __builtin_amdgcn_s_barrier();

    // frag arrays: af[m*2+kk] (row-blocks 0,1), bf[nb*2+kk]
    short8 bfX[4], afX[4], bfY[4], afY[4];
    {
        const unsigned short* Ar0 = &lds[0];
        bfX[0] = *(const short8*)&Ar0[bbase32 + sw0];
        bfX[1] = *(const short8*)&Ar0[bbase32 + sw1];
        bfX[2] = *(const short8*)&Ar0[bbase32 + 1024 + sw0];
        bfX[3] = *(const short8*)&Ar0[bbase32 + 1024 + sw1];
        afX[0] = *(const short8*)&Ar0[abase32 + sw0];
        afX[1] = *(const short8*)&Ar0[abase32 + sw1];
        afX[2] = *(const short8*)&Ar0[abase32 + 1024 + sw0];
        afX[3] = *(const short8*)&Ar0[abase32 + 1024 + sw1];
    }

// one phase: e_ = p&3 compile-time; bfC/afC read @p-1, fills bfN/afN for p+1
#define PHASE(e_, bfC, afC, bfN, afN, jj) do {                                  \
        asm volatile("s_waitcnt vmcnt(4)");                                     \
        __builtin_amdgcn_s_barrier();                                           \
        __builtin_amdgcn_sched_barrier(0);                                      \
        const unsigned short* ArC = &lds[(e_) * 16384];                         \
        const unsigned short* ArN = &lds[(((e_) + 1) & 3) * 16384];             \
        short8 af2[4];                                                          \
        af2[0] = *(const short8*)&ArC[abase32 + 2048 + sw0];                    \
        af2[1] = *(const short8*)&ArC[abase32 + 2048 + sw1];                    \
        af2[2] = *(const short8*)&ArC[abase32 + 3072 + sw0];                    \
        af2[3] = *(const short8*)&ArC[abase32 + 3072 + sw1];                    \
        bfN[0] = *(const short8*)&ArN[bbase32 + sw0];                           \
        bfN[1] = *(const short8*)&ArN[bbase32 + sw1];                           \
        bfN[2] = *(const short8*)&ArN[bbase32 + 1024 + sw0];                    \
        bfN[3] = *(const short8*)&ArN[bbase32 + 1024 + sw1];                    \
        afN[0] = *(const short8*)&ArN[abase32 + sw0];                           \
        afN[1] = *(const short8*)&ArN[abase32 + sw1];                           \
        afN[2] = *(const short8*)&ArN[abase32 + 1024 + sw0];                    \
        afN[3] = *(const short8*)&ArN[abase32 + 1024 + sw1];                    \
        STAGE(4 * (jj) + (e_) + 3, ((e_) + 3) & 3);                             \
        __builtin_amdgcn_sched_barrier(0);                                      \
        __builtin_amdgcn_s_setprio(1);                                          \
        _Pragma("unroll")                                                       \
        for (int m = 0; m < 2; ++m)                                             \
            _Pragma("unroll")                                                   \
            for (int nb = 0; nb < 2; ++nb)                                      \
                _Pragma("unroll")                                               \
                for (int kk = 0; kk < 2; ++kk)                                  \
                    acc[m][nb] = __builtin_amdgcn_mfma_f32_32x32x16_bf16(       \
                        afC[m * 2 + kk], bfC[nb * 2 + kk], acc[m][nb], 0, 0, 0);\
        _Pragma("unroll")                                                       \
        for (int m = 0; m < 2; ++m)                                             \
            _Pragma("unroll")                                                   \
            for (int nb = 0; nb < 2; ++nb)                                      \
                _Pragma("unroll")                                               \
                for (int kk = 0; kk < 2; ++kk)                                  \
                    acc[2 + m][nb] = __builtin_amdgcn_mfma_f32_32x32x16_bf16(   \
                        af2[m * 2 + kk], bfC[nb * 2 + kk], acc[2 + m][nb], 0, 0, 0);\
        __builtin_amdgcn_s_setprio(0);                                          \
    } while (0)

#pragma unroll 1
    for (int j = 0; j < GK / 128; ++j) {   // 32 iters x 4 phases (BK=32 each)
        PHASE(0, bfX, afX, bfY, afY, j);
        PHASE(1, bfY, afY, bfX, afX, j);
        PHASE(2, bfX, afX, bfY, afY, j);
        PHASE(3, bfY, afY, bfX, afX, j);
    }
#undef PHASE
#undef STAGE

    // epilogue: C/D layout col=lane&31, row=(reg&3)+8*(reg>>2)+4*(lane>>5)
    for (int mb = 0; mb < 4; ++mb) {
        for (int nb = 0; nb < 2; ++nb) {
            const int r00 = m0 + wm * 128 + mb * 32 + 4 * jsel;
            const int cc  = n0 + wn * 64 + nb * 32 + frow32;
            #pragma unroll
            for (int g = 0; g < 4; ++g)
                #pragma unroll
                for (int rr = 0; rr < 4; ++rr)
                    C[(size_t)(r00 + g * 8 + rr) * GN + cc] = acc[mb][nb][g * 4 + rr];
        }
    }
}

// ---------------------------------------------------------------------------
// Fallback SpMM path (round-1 kernel) if workspace is too small for densify
// ---------------------------------------------------------------------------
#define WS_COUNTS  0
#define WS_OFFSETS 4097
#define WS_CURSOR  8194
#define WS_HEADER  12290

__global__ void hist_kernel(const int* __restrict__ rows, int* __restrict__ counts, int nnz) {
    int i = blockIdx.x * blockDim.x + threadIdx.x;
    if (i < nnz) atomicAdd(&counts[rows[i]], 1);
}

__global__ void scan_kernel(const int* __restrict__ counts, int* __restrict__ offsets) {
    __shared__ int lsum[256];
    int t = threadIdx.x;
    int base = t * 16;
    int local[16];
    int s = 0;
    for (int i = 0; i < 16; ++i) { local[i] = counts[base + i]; s += local[i]; }
    lsum[t] = s;
    __syncthreads();
    if (t == 0) {
        int acc = 0;
        for (int i = 0; i < 256; ++i) { int v = lsum[i]; lsum[i] = acc; acc += v; }
        offsets[OUT_F] = acc;
    }
    __syncthreads();
    int acc = lsum[t];
    for (int i = 0; i < 16; ++i) { offsets[base + i] = acc; acc += local[i]; }
}

__global__ void scatter_kernel(const int* __restrict__ rows, const int* __restrict__ cols,
                               const float* __restrict__ vals,
                               const int* __restrict__ offsets, int* __restrict__ cursor,
                               int* __restrict__ cols_s, float* __restrict__ vals_s, int nnz) {
    int i = blockIdx.x * blockDim.x + threadIdx.x;
    if (i < nnz) {
        int r = rows[i];
        int pos = offsets[r] + atomicAdd(&cursor[r], 1);
        cols_s[pos] = cols[i];
        vals_s[pos] = vals[i];
    }
}

__global__ __launch_bounds__(256) void spmm_kernel(const int* __restrict__ offsets,
                                                   const int* __restrict__ cols_s,
                                                   const float* __restrict__ vals_s,
                                                   const float* __restrict__ x,
                                                   float* __restrict__ out) {
    const int row  = blockIdx.x;
    const int col0 = blockIdx.y * 1024 + threadIdx.x * 4;
    const int k0 = offsets[row];
    const int k1 = offsets[row + 1];
    float4 acc = make_float4(0.f, 0.f, 0.f, 0.f);
    for (int k = k0; k < k1; ++k) {
        const int   c = cols_s[k];
        const float v = vals_s[k];
        const float4 xv = *reinterpret_cast<const float4*>(x + (size_t)c * NCOLS + col0);
        acc.x += v * xv.x;
        acc.y += v * xv.y;
        acc.z += v * xv.z;
        acc.w += v * xv.w;
    }
    *reinterpret_cast<float4*>(out + (size_t)row * NCOLS + col0) = acc;
}

// ---------------------------------------------------------------------------
extern "C" void kernel_launch(void* const* d_in, const int* in_sizes, int n_in,
                              void* d_out, int out_size, void* d_ws, size_t ws_size,
                              hipStream_t stream) {
    const int*   rows = (const int*)d_in[0];
    const int*   cols = (const int*)d_in[1];
    const float* vals = (const float*)d_in[2];
    const float* x    = (const float*)d_in[3];
    float*       out  = (float*)d_out;
    const int nnz = in_sizes[0];

    const size_t WF_BYTES = (size_t)GM * GK * 4;   // 64 MB fp32 W (later reused for xT)
    const size_t WB_BYTES = (size_t)GM * GK * 2;   // 32 MB bf16 W
    const size_t NEED = WF_BYTES + WB_BYTES;       // 96 MB

    if (ws_size >= NEED) {
        float*          Wf = (float*)d_ws;
        unsigned short* Wb = (unsigned short*)((char*)d_ws + WF_BYTES);
        unsigned short* xT = (unsigned short*)d_ws;  // reuses Wf region after convert_w

        hipMemsetAsync(Wf, 0, WF_BYTES, stream);
        scatter_dense<<<(nnz + 255) / 256, 256, 0, stream>>>(rows, cols, vals, Wf, nnz);
        convert_w<<<(GM * GK / 4) / 256, 256, 0, stream>>>(Wf, Wb);
        // Wf is dead now; overwrite its region with xT
        dim3 tg(GK / 64, GN / 64);
        transpose_x<<<tg, 256, 0, stream>>>(x, xT);
        dim3 gg(GN / 256, GM / 256);
        gemm256<<<gg, 512, 0, stream>>>(Wb, xT, out);
    } else {
        // fallback: CSR SpMM (round-1 path)
        int*   ws_i    = (int*)d_ws;
        int*   counts  = ws_i + WS_COUNTS;
        int*   offsets = ws_i + WS_OFFSETS;
        int*   cursor  = ws_i + WS_CURSOR;
        int*   cols_s  = ws_i + WS_HEADER;
        float* vals_s  = (float*)(ws_i + WS_HEADER + nnz);

        hipMemsetAsync(d_ws, 0, (size_t)WS_HEADER * sizeof(int), stream);
        const int nblk = (nnz + 255) / 256;
        hist_kernel<<<nblk, 256, 0, stream>>>(rows, counts, nnz);
        scan_kernel<<<1, 256, 0, stream>>>(counts, offsets);
        scatter_kernel<<<nblk, 256, 0, stream>>>(rows, cols, vals, offsets, cursor,
                                                 cols_s, vals_s, nnz);
        dim3 grid(OUT_F, NCOLS / 1024);
        spmm_kernel<<<grid, 256, 0, stream>>>(offsets, cols_s, vals_s, x, out);
    }
}